// Round 2
// baseline (3705.257 us; speedup 1.0000x reference)
//
#include <hip/hip_runtime.h>
#include <cstdint>
#include <cstddef>

#define B_     4
#define N_     10000
#define E_     320000
#define FN_    16
#define INDIM  33
#define EH     64
#define EH2    32
#define EOUT   64
#define NHID   12
#define CH     64
#define NCHUNK 157   // ceil(10000/64)

// ws layout (bytes):
//   [0,    628)  counts[157]
//   [1024, 1656) offsets[158]
//   [2048, 2676) cursors[157]
//   [4096, ... ) entries[2*E] uint2  (5.12 MB)
// entry.x = e | (isSrc<<19) | (own_local<<20) ; entry.y = other node
// (e < 320000 < 2^19; own_local < 64)

__device__ __forceinline__ float f4get(const float4& v, int k) {
    switch (k) { case 0: return v.x; case 1: return v.y; case 2: return v.z; default: return v.w; }
}
__device__ __forceinline__ void fma4(float4& a, float s, const float4 w) {
    a.x = fmaf(s, w.x, a.x); a.y = fmaf(s, w.y, a.y);
    a.z = fmaf(s, w.z, a.z); a.w = fmaf(s, w.w, a.w);
}
__device__ __forceinline__ void relu4(float4& a) {
    a.x = fmaxf(a.x, 0.f); a.y = fmaxf(a.y, 0.f);
    a.z = fmaxf(a.z, 0.f); a.w = fmaxf(a.w, 0.f);
}

__global__ __launch_bounds__(256) void hist_kernel(
    const int* __restrict__ esrc, const int* __restrict__ etgt,
    int* __restrict__ counts)
{
    __shared__ int hc[NCHUNK];
    const int tid = threadIdx.x;
    for (int i = tid; i < NCHUNK; i += 256) hc[i] = 0;
    __syncthreads();
    const int e = blockIdx.x * 256 + tid;          // E_ % 256 == 0
    atomicAdd(&hc[esrc[e] >> 6], 1);
    atomicAdd(&hc[etgt[e] >> 6], 1);
    __syncthreads();
    for (int i = tid; i < NCHUNK; i += 256)
        if (hc[i]) atomicAdd(&counts[i], hc[i]);
}

__global__ void scan_kernel(const int* __restrict__ counts,
                            int* __restrict__ offsets,
                            int* __restrict__ cursors)
{
    if (threadIdx.x == 0) {
        int acc = 0;
        for (int i = 0; i < NCHUNK; i++) {
            offsets[i] = acc;
            cursors[i] = acc;
            acc += counts[i];
        }
        offsets[NCHUNK] = acc;
    }
}

__global__ __launch_bounds__(256) void fill_kernel(
    const int* __restrict__ esrc, const int* __restrict__ etgt,
    int* __restrict__ cursors, uint2* __restrict__ entries)
{
    const int e = blockIdx.x * 256 + threadIdx.x;
    const int s = esrc[e], t = etgt[e];
    int p = atomicAdd(&cursors[s >> 6], 1);
    entries[p] = make_uint2((unsigned)e | (1u << 19) | ((unsigned)(s & 63) << 20), (unsigned)t);
    p = atomicAdd(&cursors[t >> 6], 1);
    entries[p] = make_uint2((unsigned)e | ((unsigned)(t & 63) << 20), (unsigned)s);
}

// One block per (chunk, batch). Edge MLP recomputed per entry; signed sigmoid
// accumulated into LDS (ds_add_f32); node MLP fused at the end.
__global__ __launch_bounds__(256, 2) void chunk_kernel(
    const float* __restrict__ nf,      // [B][N][16]
    const float* __restrict__ ew,      // [B][E]
    const float* __restrict__ lp,      // [B][N]
    const uint2* __restrict__ entries,
    const int*   __restrict__ offsets,
    const float* __restrict__ W1, const float* __restrict__ b1,
    const float* __restrict__ W2, const float* __restrict__ b2,
    const float* __restrict__ W3, const float* __restrict__ b3,
    const float* __restrict__ W4, const float* __restrict__ b4,
    const float* __restrict__ W5, const float* __restrict__ b5,
    float* __restrict__ out)           // [B][N]
{
    __shared__ float sW1[INDIM * EH];      // 8448 B
    __shared__ float sb1[EH];
    __shared__ float sW2[EH * EH2];        // 8192 B
    __shared__ float sb2[EH2];
    __shared__ float sown[CH][20];         // own-node features, 80B rows (16B aligned)
    __shared__ float sagg[CH][68];         // accumulator, 272B rows (16B aligned)
    __shared__ float sh2[4][64][36];       // per-wave h2 staging
    __shared__ unsigned int sidx[4][64];
    __shared__ float sW4[(EOUT + 1) * NHID];
    __shared__ float sb4[NHID];
    __shared__ float sW5[NHID];
    __shared__ float sb5v;

    const int tid   = threadIdx.x;
    const int c     = blockIdx.x;
    const int b     = blockIdx.y;
    const int node0 = c * CH;
    const int nvalid = min(CH, N_ - node0);

    for (int i = tid; i < INDIM * EH; i += 256) sW1[i] = W1[i];
    for (int i = tid; i < EH * EH2;   i += 256) sW2[i] = W2[i];
    for (int i = tid; i < (EOUT + 1) * NHID; i += 256) sW4[i] = W4[i];
    if (tid < EH)  sb1[tid] = b1[tid];
    if (tid < EH2) sb2[tid] = b2[tid];
    if (tid < NHID) { sb4[tid] = b4[tid]; sW5[tid] = W5[tid]; }
    if (tid == 0) sb5v = b5[0];
    for (int i = tid; i < CH * FN_; i += 256) {
        int r = i >> 4, q = i & 15;
        sown[r][q] = (r < nvalid) ? nf[((size_t)b * N_ + node0 + r) * FN_ + q] : 0.f;
    }
    {
        float* sa = &sagg[0][0];
        for (int i = tid; i < CH * 68; i += 256) sa[i] = 0.f;
    }

    const int wv = tid >> 6, ln = tid & 63;

    // per-lane W3 column + bias (lane = output channel)
    float w3c[32];
    #pragma unroll
    for (int i = 0; i < 32; i++) w3c[i] = W3[i * EOUT + ln];
    const float bias3 = b3[ln];

    __syncthreads();

    const int beg = offsets[c], end = offsets[c + 1];

    for (int base = beg + wv * 64; base < end; base += 256) {
        const int  idx   = base + ln;
        const bool valid = (idx < end);
        uint2 ent = valid ? entries[idx] : make_uint2(0u, 0u);
        const int e     = (int)(ent.x & 0x7FFFFu);
        const int isSrc = (int)((ent.x >> 19) & 1u);
        const int own   = (int)((ent.x >> 20) & 63u);
        const int other = (int)ent.y;

        const float w = ew[(size_t)b * E_ + e];

        float4 ro[4];
        {
            const float4* po = (const float4*)(nf + ((size_t)b * N_ + other) * FN_);
            ro[0] = po[0]; ro[1] = po[1]; ro[2] = po[2]; ro[3] = po[3];
        }
        float4 rw[4];
        {
            const float4* pw = (const float4*)&sown[own][0];
            rw[0] = pw[0]; rw[1] = pw[1]; rw[2] = pw[2]; rw[3] = pw[3];
        }

        // e_in = [nf[src], nf[tgt], w] ; if we own src, own-row goes first
        float4 inv[8];
        if (isSrc) {
            inv[0] = rw[0]; inv[1] = rw[1]; inv[2] = rw[2]; inv[3] = rw[3];
            inv[4] = ro[0]; inv[5] = ro[1]; inv[6] = ro[2]; inv[7] = ro[3];
        } else {
            inv[0] = ro[0]; inv[1] = ro[1]; inv[2] = ro[2]; inv[3] = ro[3];
            inv[4] = rw[0]; inv[5] = rw[1]; inv[6] = rw[2]; inv[7] = rw[3];
        }

        // ---- layer 1: 33 -> 64, relu ----
        float4 h1[16];
        {
            const float4* bv = (const float4*)sb1;
            #pragma unroll
            for (int j = 0; j < 16; j++) h1[j] = bv[j];
        }
        #pragma unroll
        for (int i = 0; i < 32; i++) {
            float v = f4get(inv[i >> 2], i & 3);
            const float4* wr = (const float4*)(sW1 + i * EH);
            #pragma unroll
            for (int j = 0; j < 16; j++) fma4(h1[j], v, wr[j]);
        }
        {
            const float4* wr = (const float4*)(sW1 + 32 * EH);
            #pragma unroll
            for (int j = 0; j < 16; j++) fma4(h1[j], w, wr[j]);
        }
        #pragma unroll
        for (int j = 0; j < 16; j++) relu4(h1[j]);

        // ---- layer 2: 64 -> 32, relu ----
        float4 h2[8];
        {
            const float4* bv = (const float4*)sb2;
            #pragma unroll
            for (int j = 0; j < 8; j++) h2[j] = bv[j];
        }
        #pragma unroll
        for (int i = 0; i < 64; i++) {
            float v = f4get(h1[i >> 2], i & 3);
            const float4* wr = (const float4*)(sW2 + i * EH2);
            #pragma unroll
            for (int j = 0; j < 8; j++) fma4(h2[j], v, wr[j]);
        }
        #pragma unroll
        for (int j = 0; j < 8; j++) relu4(h2[j]);

        {
            float4* dst = (float4*)&sh2[wv][ln][0];
            #pragma unroll
            for (int j = 0; j < 8; j++) dst[j] = h2[j];
            sidx[wv][ln] = (unsigned)own | ((unsigned)isSrc << 6) | (valid ? 0x80u : 0u);
        }

        // ---- layer 3 (transposed): 32 -> 64, sigmoid, signed LDS scatter ----
        for (int ee = 0; ee < 64; ee++) {
            unsigned m = sidx[wv][ee];           // wave-uniform broadcast
            if (!(m & 0x80u)) continue;
            const float4* hp = (const float4*)&sh2[wv][ee][0];
            float acc = bias3;
            #pragma unroll
            for (int cc = 0; cc < 8; cc++) {
                float4 hh = hp[cc];
                acc = fmaf(hh.x, w3c[4 * cc + 0], acc);
                acc = fmaf(hh.y, w3c[4 * cc + 1], acc);
                acc = fmaf(hh.z, w3c[4 * cc + 2], acc);
                acc = fmaf(hh.w, w3c[4 * cc + 3], acc);
            }
            float s = 1.0f / (1.0f + __expf(-acc));
            if (m & 0x40u) s = -s;               // own==src -> subtract
            atomicAdd(&sagg[m & 63u][ln], s);    // ds_add_f32
        }
    }

    __syncthreads();

    // ---- fused node MLP: 65 -> 12 -> 1 ----
    if (tid < nvalid) {
        float nh[NHID];
        #pragma unroll
        for (int j = 0; j < NHID; j++) nh[j] = sb4[j];

        const float* ar = &sagg[tid][0];
        #pragma unroll
        for (int k = 0; k < EOUT; k++) {
            float v = ar[k];
            const float* wr = sW4 + k * NHID;
            #pragma unroll
            for (int j = 0; j < NHID; j++) nh[j] = fmaf(v, wr[j], nh[j]);
        }
        {
            float v = lp[(size_t)b * N_ + node0 + tid];
            const float* wr = sW4 + EOUT * NHID;
            #pragma unroll
            for (int j = 0; j < NHID; j++) nh[j] = fmaf(v, wr[j], nh[j]);
        }
        float acc = sb5v;
        #pragma unroll
        for (int j = 0; j < NHID; j++) acc = fmaf(fmaxf(nh[j], 0.f), sW5[j], acc);
        out[(size_t)b * N_ + node0 + tid] = 1.0f / (1.0f + __expf(-acc));
    }
}

extern "C" void kernel_launch(void* const* d_in, const int* in_sizes, int n_in,
                              void* d_out, int out_size, void* d_ws, size_t ws_size,
                              hipStream_t stream)
{
    const float* nf   = (const float*)d_in[0];
    const float* ew   = (const float*)d_in[1];
    const float* lp   = (const float*)d_in[2];
    const int*   esrc = (const int*)d_in[3];
    const int*   etgt = (const int*)d_in[4];
    const float* W1 = (const float*)d_in[5],  *b1 = (const float*)d_in[6];
    const float* W2 = (const float*)d_in[7],  *b2 = (const float*)d_in[8];
    const float* W3 = (const float*)d_in[9],  *b3 = (const float*)d_in[10];
    const float* W4 = (const float*)d_in[11], *b4 = (const float*)d_in[12];
    const float* W5 = (const float*)d_in[13], *b5 = (const float*)d_in[14];

    float* out = (float*)d_out;

    char* ws = (char*)d_ws;
    int*   counts  = (int*)(ws + 0);
    int*   offsets = (int*)(ws + 1024);
    int*   cursors = (int*)(ws + 2048);
    uint2* entries = (uint2*)(ws + 4096);

    hipMemsetAsync(counts, 0, 1024, stream);

    hist_kernel<<<E_ / 256, 256, 0, stream>>>(esrc, etgt, counts);
    scan_kernel<<<1, 64, 0, stream>>>(counts, offsets, cursors);
    fill_kernel<<<E_ / 256, 256, 0, stream>>>(esrc, etgt, cursors, entries);

    dim3 cg(NCHUNK, B_);
    chunk_kernel<<<cg, 256, 0, stream>>>(nf, ew, lp, entries, offsets,
                                         W1, b1, W2, b2, W3, b3,
                                         W4, b4, W5, b5, out);
}

// Round 3
// 1547.102 us; speedup vs baseline: 2.3950x; 2.3950x over previous
//
#include <hip/hip_runtime.h>
#include <cstdint>
#include <cstddef>

#define B_     4
#define N_     10000
#define E_     320000
#define FN_    16
#define INDIM  33
#define EH     64
#define EH2    32
#define EOUT   64
#define NHID   12
#define CH2    32
#define NCHUNK2 313   // ceil(10000/32)

// ws layout (bytes):
//   [0,      1252)  counts[313]
//   [2048,   3304)  offsets[314]
//   [4096,   5348)  cursors[313]
//   [8192,   +2.56M) entries[2*E] uint32  (e | isSrc<<19 | own_local<<20)
//   [4 MiB,  ...  )  h fp16: [nb][E][64]  (nb = 4 full tier, 1 per-batch tier)

__device__ __forceinline__ float f4get(const float4& v, int k) {
    switch (k) { case 0: return v.x; case 1: return v.y; case 2: return v.z; default: return v.w; }
}
__device__ __forceinline__ void fma4(float4& a, float s, const float4 w) {
    a.x = fmaf(s, w.x, a.x); a.y = fmaf(s, w.y, a.y);
    a.z = fmaf(s, w.z, a.z); a.w = fmaf(s, w.w, a.w);
}
__device__ __forceinline__ void relu4(float4& a) {
    a.x = fmaxf(a.x, 0.f); a.y = fmaxf(a.y, 0.f);
    a.z = fmaxf(a.z, 0.f); a.w = fmaxf(a.w, 0.f);
}

// ---------------- pre-passes: build per-chunk entry lists ----------------

__global__ __launch_bounds__(256) void hist_kernel(
    const int* __restrict__ esrc, const int* __restrict__ etgt,
    int* __restrict__ counts)
{
    __shared__ int hc[NCHUNK2];
    const int tid = threadIdx.x;
    for (int i = tid; i < NCHUNK2; i += 256) hc[i] = 0;
    __syncthreads();
    const int e = blockIdx.x * 256 + tid;          // E_ % 256 == 0
    atomicAdd(&hc[esrc[e] >> 5], 1);
    atomicAdd(&hc[etgt[e] >> 5], 1);
    __syncthreads();
    for (int i = tid; i < NCHUNK2; i += 256)
        if (hc[i]) atomicAdd(&counts[i], hc[i]);
}

__global__ void scan_kernel(const int* __restrict__ counts,
                            int* __restrict__ offsets,
                            int* __restrict__ cursors)
{
    if (threadIdx.x == 0) {
        int acc = 0;
        for (int i = 0; i < NCHUNK2; i++) {
            offsets[i] = acc;
            cursors[i] = acc;
            acc += counts[i];
        }
        offsets[NCHUNK2] = acc;
    }
}

__global__ __launch_bounds__(256) void fill_kernel(
    const int* __restrict__ esrc, const int* __restrict__ etgt,
    int* __restrict__ cursors, unsigned* __restrict__ entries)
{
    const int e = blockIdx.x * 256 + threadIdx.x;
    const int s = esrc[e], t = etgt[e];
    int p = atomicAdd(&cursors[s >> 5], 1);
    entries[p] = (unsigned)e | (1u << 19) | ((unsigned)(s & 31) << 20);  // src side: -h
    p = atomicAdd(&cursors[t >> 5], 1);
    entries[p] = (unsigned)e | ((unsigned)(t & 31) << 20);               // tgt side: +h
}

// ---------------- pass A: edge MLP, coalesced, h -> fp16 ----------------
// Round-1 structure (proven): per-thread layers 1-2, transposed layer 3
// (lane = output channel), but the atomic scatter is replaced by one
// coalesced 128 B fp16 store per edge. No global atomics.

__global__ __launch_bounds__(256, 3) void edge_h_kernel(
    const float* __restrict__ nf,     // [B][N][16]
    const float* __restrict__ ew,     // [B][E]
    const int*   __restrict__ esrc,
    const int*   __restrict__ etgt,
    const float* __restrict__ W1, const float* __restrict__ b1,
    const float* __restrict__ W2, const float* __restrict__ b2,
    const float* __restrict__ W3, const float* __restrict__ b3,
    _Float16* __restrict__ h16,       // [grid.y][E][64]
    int bbase)
{
    __shared__ float sW1[INDIM * EH];     // 8448 B
    __shared__ float sb1[EH];
    __shared__ float sW2[EH * EH2];       // 8192 B
    __shared__ float sb2[EH2];
    __shared__ float sh2[4][64][36];      // 36864 B (144 B rows, 16 B aligned)

    const int tid = threadIdx.x;
    const int hb  = blockIdx.y;           // h slab index
    const int b   = bbase + hb;           // data batch

    for (int i = tid; i < INDIM * EH; i += 256) sW1[i] = W1[i];
    for (int i = tid; i < EH * EH2;   i += 256) sW2[i] = W2[i];
    if (tid < EH)  sb1[tid] = b1[tid];
    if (tid < EH2) sb2[tid] = b2[tid];

    const int e   = blockIdx.x * 256 + tid;
    const int src = esrc[e];
    const int tgt = etgt[e];
    const float w = ew[(size_t)b * E_ + e];

    float4 inv[8];
    {
        const float4* ps = (const float4*)(nf + ((size_t)b * N_ + src) * FN_);
        const float4* pt = (const float4*)(nf + ((size_t)b * N_ + tgt) * FN_);
        inv[0] = ps[0]; inv[1] = ps[1]; inv[2] = ps[2]; inv[3] = ps[3];
        inv[4] = pt[0]; inv[5] = pt[1]; inv[6] = pt[2]; inv[7] = pt[3];
    }

    __syncthreads();   // weights staged

    // ---- layer 1: 33 -> 64, relu ----
    float4 h1[16];
    {
        const float4* bv = (const float4*)sb1;
        #pragma unroll
        for (int j = 0; j < 16; j++) h1[j] = bv[j];
    }
    #pragma unroll
    for (int i = 0; i < 32; i++) {
        float v = f4get(inv[i >> 2], i & 3);
        const float4* wr = (const float4*)(sW1 + i * EH);
        #pragma unroll
        for (int j = 0; j < 16; j++) fma4(h1[j], v, wr[j]);
    }
    {
        const float4* wr = (const float4*)(sW1 + 32 * EH);
        #pragma unroll
        for (int j = 0; j < 16; j++) fma4(h1[j], w, wr[j]);
    }
    #pragma unroll
    for (int j = 0; j < 16; j++) relu4(h1[j]);

    // ---- layer 2: 64 -> 32, relu ----
    float4 h2[8];
    {
        const float4* bv = (const float4*)sb2;
        #pragma unroll
        for (int j = 0; j < 8; j++) h2[j] = bv[j];
    }
    #pragma unroll
    for (int i = 0; i < 64; i++) {
        float v = f4get(h1[i >> 2], i & 3);
        const float4* wr = (const float4*)(sW2 + i * EH2);
        #pragma unroll
        for (int j = 0; j < 8; j++) fma4(h2[j], v, wr[j]);
    }
    #pragma unroll
    for (int j = 0; j < 8; j++) relu4(h2[j]);

    const int wv = tid >> 6, ln = tid & 63;
    {
        float4* dst = (float4*)&sh2[wv][ln][0];
        #pragma unroll
        for (int j = 0; j < 8; j++) dst[j] = h2[j];
    }

    // per-lane W3 column + bias (lane = output channel); coalesced loads
    float w3c[32];
    #pragma unroll
    for (int i = 0; i < 32; i++) w3c[i] = W3[i * EOUT + ln];
    const float bias3 = b3[ln];

    __syncthreads();   // sh2 staged

    // ---- layer 3 (transposed): 32 -> 64, sigmoid, coalesced fp16 store ----
    const int e0 = blockIdx.x * 256 + wv * 64;
    _Float16* hout = h16 + ((size_t)hb * E_ + e0) * EOUT + ln;
    for (int ee = 0; ee < 64; ee++) {
        const float4* hp = (const float4*)&sh2[wv][ee][0];   // broadcast reads
        float acc = bias3;
        #pragma unroll
        for (int cc = 0; cc < 8; cc++) {
            float4 hh = hp[cc];
            acc = fmaf(hh.x, w3c[4 * cc + 0], acc);
            acc = fmaf(hh.y, w3c[4 * cc + 1], acc);
            acc = fmaf(hh.z, w3c[4 * cc + 2], acc);
            acc = fmaf(hh.w, w3c[4 * cc + 3], acc);
        }
        float s = 1.0f / (1.0f + __expf(-acc));
        hout[(size_t)ee * EOUT] = (_Float16)s;   // 128 B/wave, coalesced
    }
}

// ---------------- pass B: gather h, LDS-accumulate, fused node MLP ----------------
// One block per (chunk of 32 nodes, batch). Per entry: wave-uniform scalar
// entry fetch + one coalesced 128 B h-row gather (lane = channel) +
// conflict-free ds_add_f32. 4 entries in flight per wave.

__global__ __launch_bounds__(256) void aggregate_kernel(
    const _Float16* __restrict__ h16,   // [grid.y][E][64]
    const float* __restrict__ lp,       // [B][N]
    const unsigned* __restrict__ entries,
    const int* __restrict__ offsets,
    const float* __restrict__ W4, const float* __restrict__ b4,
    const float* __restrict__ W5, const float* __restrict__ b5,
    float* __restrict__ out,            // [B][N]
    int bbase)
{
    __shared__ float sagg[CH2][68];     // 8704 B (272 B rows: 2-way banks, free)
    __shared__ float sW4[(EOUT + 1) * NHID];
    __shared__ float sb4[NHID];
    __shared__ float sW5[NHID];
    __shared__ float sb5v;

    const int tid = threadIdx.x;
    const int c   = blockIdx.x;
    const int hb  = blockIdx.y;
    const int b   = bbase + hb;
    const int node0  = c * CH2;
    const int nvalid = min(CH2, N_ - node0);

    for (int i = tid; i < (EOUT + 1) * NHID; i += 256) sW4[i] = W4[i];
    if (tid < NHID) { sb4[tid] = b4[tid]; sW5[tid] = W5[tid]; }
    if (tid == 0) sb5v = b5[0];
    {
        float* sa = &sagg[0][0];
        for (int i = tid; i < CH2 * 68; i += 256) sa[i] = 0.f;
    }
    __syncthreads();

    const int beg = offsets[c], end = offsets[c + 1];
    const int wv = tid >> 6, ln = tid & 63;
    const _Float16* hbase = h16 + (size_t)hb * E_ * EOUT + ln;

    for (int it = beg + wv * 4; it < end; it += 16) {
        const int n0 = min(4, end - it);          // wave-uniform
        unsigned ent[4];
        float    hv[4];
        #pragma unroll
        for (int k = 0; k < 4; k++)
            if (k < n0) ent[k] = entries[it + k];  // wave-uniform -> s_load
        #pragma unroll
        for (int k = 0; k < 4; k++)
            if (k < n0) hv[k] = (float)hbase[(size_t)(ent[k] & 0x7FFFFu) * EOUT];
        #pragma unroll
        for (int k = 0; k < 4; k++)
            if (k < n0) {
                float s = ((ent[k] >> 19) & 1u) ? -hv[k] : hv[k];
                atomicAdd(&sagg[(ent[k] >> 20) & 31u][ln], s);   // ds_add_f32
            }
    }

    __syncthreads();

    // ---- fused node MLP: 65 -> 12 -> 1 ----
    if (tid < nvalid) {
        float nh[NHID];
        #pragma unroll
        for (int j = 0; j < NHID; j++) nh[j] = sb4[j];

        const float* ar = &sagg[tid][0];
        #pragma unroll
        for (int k = 0; k < EOUT; k++) {
            float v = ar[k];
            const float* wr = sW4 + k * NHID;
            #pragma unroll
            for (int j = 0; j < NHID; j++) nh[j] = fmaf(v, wr[j], nh[j]);
        }
        {
            float v = lp[(size_t)b * N_ + node0 + tid];
            const float* wr = sW4 + EOUT * NHID;
            #pragma unroll
            for (int j = 0; j < NHID; j++) nh[j] = fmaf(v, wr[j], nh[j]);
        }
        float acc = sb5v;
        #pragma unroll
        for (int j = 0; j < NHID; j++) acc = fmaf(fmaxf(nh[j], 0.f), sW5[j], acc);
        out[(size_t)b * N_ + node0 + tid] = 1.0f / (1.0f + __expf(-acc));
    }
}

// ---------------- legacy fallback (round-1 kernels, atomic path) ----------------

__global__ __launch_bounds__(256, 2) void edge_kernel_legacy(
    const float* __restrict__ nf, const float* __restrict__ ew,
    const int* __restrict__ esrc, const int* __restrict__ etgt,
    const float* __restrict__ W1, const float* __restrict__ b1,
    const float* __restrict__ W2, const float* __restrict__ b2,
    const float* __restrict__ W3, const float* __restrict__ b3,
    float* __restrict__ agg)
{
    __shared__ float sW1[INDIM * EH];
    __shared__ float sb1[EH];
    __shared__ float sW2[EH * EH2];
    __shared__ float sb2[EH2];
    __shared__ float sh2[4][64][36];
    __shared__ int   sidx[4][64][2];

    const int tid = threadIdx.x;
    const int b   = blockIdx.y;

    for (int i = tid; i < INDIM * EH; i += 256) sW1[i] = W1[i];
    for (int i = tid; i < EH * EH2;   i += 256) sW2[i] = W2[i];
    if (tid < EH)  sb1[tid] = b1[tid];
    if (tid < EH2) sb2[tid] = b2[tid];

    const int e   = blockIdx.x * 256 + tid;
    const int src = esrc[e];
    const int tgt = etgt[e];
    const float w = ew[(size_t)b * E_ + e];

    float4 inv[8];
    {
        const float4* ps = (const float4*)(nf + ((size_t)b * N_ + src) * FN_);
        const float4* pt = (const float4*)(nf + ((size_t)b * N_ + tgt) * FN_);
        inv[0] = ps[0]; inv[1] = ps[1]; inv[2] = ps[2]; inv[3] = ps[3];
        inv[4] = pt[0]; inv[5] = pt[1]; inv[6] = pt[2]; inv[7] = pt[3];
    }
    __syncthreads();

    float4 h1[16];
    {
        const float4* bv = (const float4*)sb1;
        #pragma unroll
        for (int j = 0; j < 16; j++) h1[j] = bv[j];
    }
    #pragma unroll
    for (int i = 0; i < 32; i++) {
        float v = f4get(inv[i >> 2], i & 3);
        const float4* wr = (const float4*)(sW1 + i * EH);
        #pragma unroll
        for (int j = 0; j < 16; j++) fma4(h1[j], v, wr[j]);
    }
    {
        const float4* wr = (const float4*)(sW1 + 32 * EH);
        #pragma unroll
        for (int j = 0; j < 16; j++) fma4(h1[j], w, wr[j]);
    }
    #pragma unroll
    for (int j = 0; j < 16; j++) relu4(h1[j]);

    float4 h2[8];
    {
        const float4* bv = (const float4*)sb2;
        #pragma unroll
        for (int j = 0; j < 8; j++) h2[j] = bv[j];
    }
    #pragma unroll
    for (int i = 0; i < 64; i++) {
        float v = f4get(h1[i >> 2], i & 3);
        const float4* wr = (const float4*)(sW2 + i * EH2);
        #pragma unroll
        for (int j = 0; j < 8; j++) fma4(h2[j], v, wr[j]);
    }
    #pragma unroll
    for (int j = 0; j < 8; j++) relu4(h2[j]);

    const int wv = tid >> 6, ln = tid & 63;
    {
        float4* dst = (float4*)&sh2[wv][ln][0];
        #pragma unroll
        for (int j = 0; j < 8; j++) dst[j] = h2[j];
        sidx[wv][ln][0] = src;
        sidx[wv][ln][1] = tgt;
    }

    float w3c[32];
    #pragma unroll
    for (int i = 0; i < 32; i++) w3c[i] = W3[i * EOUT + ln];
    const float bias3 = b3[ln];

    __syncthreads();

    float* aggB = agg + (size_t)b * N_ * EOUT;
    for (int ee = 0; ee < 64; ee++) {
        const float4* hp = (const float4*)&sh2[wv][ee][0];
        float acc = bias3;
        #pragma unroll
        for (int cc = 0; cc < 8; cc++) {
            float4 hh = hp[cc];
            acc = fmaf(hh.x, w3c[4 * cc + 0], acc);
            acc = fmaf(hh.y, w3c[4 * cc + 1], acc);
            acc = fmaf(hh.z, w3c[4 * cc + 2], acc);
            acc = fmaf(hh.w, w3c[4 * cc + 3], acc);
        }
        float s = 1.0f / (1.0f + __expf(-acc));
        int t2 = sidx[wv][ee][1];
        int s2 = sidx[wv][ee][0];
        atomicAdd(aggB + (size_t)t2 * EOUT + ln,  s);
        atomicAdd(aggB + (size_t)s2 * EOUT + ln, -s);
    }
}

__global__ __launch_bounds__(256) void node_kernel_legacy(
    const float* __restrict__ agg, const float* __restrict__ lp,
    const float* __restrict__ W4, const float* __restrict__ b4,
    const float* __restrict__ W5, const float* __restrict__ b5,
    float* __restrict__ out)
{
    __shared__ float sW4[65 * NHID];
    __shared__ float sb4[NHID];
    __shared__ float sW5[NHID];
    __shared__ float sb5;

    const int tid = threadIdx.x;
    for (int i = tid; i < 65 * NHID; i += 256) sW4[i] = W4[i];
    if (tid < NHID) { sb4[tid] = b4[tid]; sW5[tid] = W5[tid]; }
    if (tid == 0) sb5 = b5[0];
    __syncthreads();

    const int idx = blockIdx.x * 256 + tid;
    if (idx >= B_ * N_) return;

    float nh[NHID];
    #pragma unroll
    for (int j = 0; j < NHID; j++) nh[j] = sb4[j];

    const float4* ar = (const float4*)(agg + (size_t)idx * EOUT);
    #pragma unroll
    for (int c = 0; c < 16; c++) {
        float4 a4 = ar[c];
        #pragma unroll
        for (int k = 0; k < 4; k++) {
            float v = f4get(a4, k);
            const float* wr = sW4 + (c * 4 + k) * NHID;
            #pragma unroll
            for (int j = 0; j < NHID; j++) nh[j] = fmaf(v, wr[j], nh[j]);
        }
    }
    {
        float v = lp[idx];
        const float* wr = sW4 + 64 * NHID;
        #pragma unroll
        for (int j = 0; j < NHID; j++) nh[j] = fmaf(v, wr[j], nh[j]);
    }
    float acc = sb5;
    #pragma unroll
    for (int j = 0; j < NHID; j++) acc = fmaf(fmaxf(nh[j], 0.f), sW5[j], acc);
    out[idx] = 1.0f / (1.0f + __expf(-acc));
}

// ---------------- launch ----------------

extern "C" void kernel_launch(void* const* d_in, const int* in_sizes, int n_in,
                              void* d_out, int out_size, void* d_ws, size_t ws_size,
                              hipStream_t stream)
{
    const float* nf   = (const float*)d_in[0];
    const float* ew   = (const float*)d_in[1];
    const float* lp   = (const float*)d_in[2];
    const int*   esrc = (const int*)d_in[3];
    const int*   etgt = (const int*)d_in[4];
    const float* W1 = (const float*)d_in[5],  *b1 = (const float*)d_in[6];
    const float* W2 = (const float*)d_in[7],  *b2 = (const float*)d_in[8];
    const float* W3 = (const float*)d_in[9],  *b3 = (const float*)d_in[10];
    const float* W4 = (const float*)d_in[11], *b4 = (const float*)d_in[12];
    const float* W5 = (const float*)d_in[13], *b5 = (const float*)d_in[14];

    float* out = (float*)d_out;
    char*  ws  = (char*)d_ws;

    const size_t H_OFF      = 4u << 20;                       // 4 MiB
    const size_t H_BATCH    = (size_t)E_ * EOUT * sizeof(_Float16);   // 40.96 MB
    const size_t NEED_FULL  = H_OFF + (size_t)B_ * H_BATCH;   // ~168 MB
    const size_t NEED_BATCH = H_OFF + H_BATCH;                // ~45.2 MB

    if (ws_size >= NEED_BATCH) {
        int*      counts  = (int*)(ws + 0);
        int*      offsets = (int*)(ws + 2048);
        int*      cursors = (int*)(ws + 4096);
        unsigned* entries = (unsigned*)(ws + 8192);
        _Float16* h16     = (_Float16*)(ws + H_OFF);

        hipMemsetAsync(counts, 0, 2048, stream);
        hist_kernel<<<E_ / 256, 256, 0, stream>>>(esrc, etgt, counts);
        scan_kernel<<<1, 64, 0, stream>>>(counts, offsets, cursors);
        fill_kernel<<<E_ / 256, 256, 0, stream>>>(esrc, etgt, cursors, entries);

        if (ws_size >= NEED_FULL) {
            dim3 ga(E_ / 256, B_);
            edge_h_kernel<<<ga, 256, 0, stream>>>(nf, ew, esrc, etgt,
                                                  W1, b1, W2, b2, W3, b3, h16, 0);
            dim3 gb(NCHUNK2, B_);
            aggregate_kernel<<<gb, 256, 0, stream>>>(h16, lp, entries, offsets,
                                                     W4, b4, W5, b5, out, 0);
        } else {
            for (int b = 0; b < B_; b++) {
                dim3 ga(E_ / 256, 1);
                edge_h_kernel<<<ga, 256, 0, stream>>>(nf, ew, esrc, etgt,
                                                      W1, b1, W2, b2, W3, b3, h16, b);
                dim3 gb(NCHUNK2, 1);
                aggregate_kernel<<<gb, 256, 0, stream>>>(h16, lp, entries, offsets,
                                                         W4, b4, W5, b5, out, b);
            }
        }
    } else {
        // legacy atomic path (round 1): needs 10.24 MB
        float* agg = (float*)d_ws;
        hipMemsetAsync(agg, 0, (size_t)B_ * N_ * EOUT * sizeof(float), stream);
        dim3 eg(E_ / 256, B_);
        edge_kernel_legacy<<<eg, 256, 0, stream>>>(nf, ew, esrc, etgt,
                                                   W1, b1, W2, b2, W3, b3, agg);
        node_kernel_legacy<<<(B_ * N_ + 255) / 256, 256, 0, stream>>>(agg, lp,
                                                   W4, b4, W5, b5, out);
    }
}

// Round 4
// 1270.626 us; speedup vs baseline: 2.9161x; 1.2176x over previous
//
#include <hip/hip_runtime.h>
#include <cstdint>
#include <cstddef>

#define B_     4
#define N_     10000
#define E_     320000
#define FN_    16
#define EH     64
#define EH2    32
#define EOUT   64
#define NHID   12
#define CH2    32
#define NCHUNK2 313   // ceil(10000/32)

typedef _Float16 v8h __attribute__((ext_vector_type(8)));
typedef float    v4f __attribute__((ext_vector_type(4)));

// ws layout (bytes):
//   [0,      1252)  counts[313]
//   [2048,   3304)  offsets[314]
//   [4096,   5348)  cursors[313]
//   [8192,   +2.56M) entries[2*E] uint32  (e | isSrc<<19 | own_local<<20)
//   [4 MiB,  ...  )  h fp16: [nb][E][64]

// ---------------- pre-passes (unchanged, proven) ----------------

__global__ __launch_bounds__(256) void hist_kernel(
    const int* __restrict__ esrc, const int* __restrict__ etgt,
    int* __restrict__ counts)
{
    __shared__ int hc[NCHUNK2];
    const int tid = threadIdx.x;
    for (int i = tid; i < NCHUNK2; i += 256) hc[i] = 0;
    __syncthreads();
    const int e = blockIdx.x * 256 + tid;
    atomicAdd(&hc[esrc[e] >> 5], 1);
    atomicAdd(&hc[etgt[e] >> 5], 1);
    __syncthreads();
    for (int i = tid; i < NCHUNK2; i += 256)
        if (hc[i]) atomicAdd(&counts[i], hc[i]);
}

__global__ void scan_kernel(const int* __restrict__ counts,
                            int* __restrict__ offsets,
                            int* __restrict__ cursors)
{
    if (threadIdx.x == 0) {
        int acc = 0;
        for (int i = 0; i < NCHUNK2; i++) {
            offsets[i] = acc; cursors[i] = acc; acc += counts[i];
        }
        offsets[NCHUNK2] = acc;
    }
}

__global__ __launch_bounds__(256) void fill_kernel(
    const int* __restrict__ esrc, const int* __restrict__ etgt,
    int* __restrict__ cursors, unsigned* __restrict__ entries)
{
    const int e = blockIdx.x * 256 + threadIdx.x;
    const int s = esrc[e], t = etgt[e];
    int p = atomicAdd(&cursors[s >> 5], 1);
    entries[p] = (unsigned)e | (1u << 19) | ((unsigned)(s & 31) << 20);
    p = atomicAdd(&cursors[t >> 5], 1);
    entries[p] = (unsigned)e | ((unsigned)(t & 31) << 20);
}

// ---------------- pass A: MFMA edge MLP -> h fp16 ----------------
// Per wave: 32-edge tile. LDS tile [32 rows][72 f16] (144 B stride, 16B-aligned).
// Layers via mfma_f32_16x16x32_f16; D layout: col=lane&15, row=(lane>>4)*4+r.
// Tile is reused in place: e_in -> h1 -> h2 -> sigmoid(S) (per-M-tile rows are
// consumed before being overwritten; all within one wave, no barriers).

__global__ __launch_bounds__(256, 4) void edge_mfma_kernel(
    const float* __restrict__ nf,     // [B][N][16]
    const float* __restrict__ ew,     // [B][E]
    const int*   __restrict__ esrc,
    const int*   __restrict__ etgt,
    const float* __restrict__ W1, const float* __restrict__ b1,
    const float* __restrict__ W2, const float* __restrict__ b2,
    const float* __restrict__ W3, const float* __restrict__ b3,
    _Float16* __restrict__ h16,       // [grid.y][E][64]
    int bbase)
{
    __shared__ __align__(16) _Float16 sT[4][32 * 72];   // 4 x 4608 B
    __shared__ __align__(16) _Float16 sW1t[64 * 72];    // [n][k] 9216 B
    __shared__ __align__(16) _Float16 sW2t[32 * 72];    // 4608 B
    __shared__ __align__(16) _Float16 sW3t[64 * 40];    // 5120 B
    __shared__ float sb1[64], sb2[32], sb3[64];

    const int tid = threadIdx.x;
    const int hb  = blockIdx.y;
    const int b   = bbase + hb;

    // ---- stage transposed, zero-padded weights (block-wide, once) ----
    {
        const int n = tid & 63, kq = tid >> 6;           // W1t: k0 = 16*kq
        const int k0 = kq * 16;
        v8h a, c;
        #pragma unroll
        for (int j = 0; j < 8; j++) {
            int k = k0 + j;     a[j] = (k < 33) ? (_Float16)W1[k * 64 + n] : (_Float16)0.f;
            int k2 = k0 + 8 + j; c[j] = (k2 < 33) ? (_Float16)W1[k2 * 64 + n] : (_Float16)0.f;
        }
        *(v8h*)&sW1t[n * 72 + k0]     = a;
        *(v8h*)&sW1t[n * 72 + k0 + 8] = c;
    }
    {
        const int n = tid & 31, kq = tid >> 5;           // W2t: k0 = 8*kq
        const int k0 = kq * 8;
        v8h a;
        #pragma unroll
        for (int j = 0; j < 8; j++) a[j] = (_Float16)W2[(k0 + j) * 32 + n];
        *(v8h*)&sW2t[n * 72 + k0] = a;
    }
    {
        const int n = tid & 63, kh = tid >> 6;           // W3t: k0 = 8*kh
        const int k0 = kh * 8;
        v8h a;
        #pragma unroll
        for (int j = 0; j < 8; j++) a[j] = (_Float16)W3[(k0 + j) * 64 + n];
        *(v8h*)&sW3t[n * 40 + k0] = a;
    }
    if (tid < 64) sb1[tid] = b1[tid];
    if (tid < 32) sb2[tid] = b2[tid];
    if (tid < 64) sb3[tid] = b3[tid];
    __syncthreads();

    const int wv = tid >> 6, ln = tid & 63;
    const int g  = ln >> 4;            // lane k-group 0..3
    const int cl = ln & 15;            // lane col/row-in-tile index
    _Float16* T = &sT[wv][0];
    const int e0 = blockIdx.x * 128 + wv * 32;

    // ---- gather + stage e_in tile (lane = half-edge) ----
    {
        const int el   = ln >> 1;              // local edge 0..31
        const int half = ln & 1;
        const int e    = e0 + el;
        const int node = half ? etgt[e] : esrc[e];
        const float4* pn = (const float4*)(nf + ((size_t)b * N_ + node) * FN_);
        float4 f0 = pn[0], f1 = pn[1], f2 = pn[2], f3 = pn[3];
        v8h c0 = { (_Float16)f0.x, (_Float16)f0.y, (_Float16)f0.z, (_Float16)f0.w,
                   (_Float16)f1.x, (_Float16)f1.y, (_Float16)f1.z, (_Float16)f1.w };
        v8h c1 = { (_Float16)f2.x, (_Float16)f2.y, (_Float16)f2.z, (_Float16)f2.w,
                   (_Float16)f3.x, (_Float16)f3.y, (_Float16)f3.z, (_Float16)f3.w };
        _Float16* rp = T + el * 72;
        *(v8h*)(rp + half * 16)     = c0;
        *(v8h*)(rp + half * 16 + 8) = c1;
        v8h z = { (_Float16)0.f, (_Float16)0.f, (_Float16)0.f, (_Float16)0.f,
                  (_Float16)0.f, (_Float16)0.f, (_Float16)0.f, (_Float16)0.f };
        if (half == 0) {
            float w = ew[(size_t)b * E_ + e];
            v8h cw = z; cw[0] = (_Float16)w;
            *(v8h*)(rp + 32) = cw;                 // k=32 (edge weight), k=33..39 zero
        } else {
            *(v8h*)(rp + 40) = z;                  // k=40..63 zero
            *(v8h*)(rp + 48) = z;
            *(v8h*)(rp + 56) = z;
        }
    }
    asm volatile("s_waitcnt lgkmcnt(0)" ::: "memory");

    // ---- layer 1: K=64 (pad), N=64, relu ----
    #pragma unroll
    for (int mt = 0; mt < 2; mt++) {
        const int arow = mt * 16 + cl;
        v8h A0 = *(const v8h*)(T + arow * 72 +      8 * g);
        v8h A1 = *(const v8h*)(T + arow * 72 + 32 + 8 * g);
        #pragma unroll
        for (int nt = 0; nt < 4; nt++) {
            const int col = cl + 16 * nt;
            float bias = sb1[col];
            v4f D = { bias, bias, bias, bias };
            v8h B0 = *(const v8h*)(&sW1t[col * 72 +      8 * g]);
            v8h B1 = *(const v8h*)(&sW1t[col * 72 + 32 + 8 * g]);
            D = __builtin_amdgcn_mfma_f32_16x16x32_f16(A0, B0, D, 0, 0, 0);
            D = __builtin_amdgcn_mfma_f32_16x16x32_f16(A1, B1, D, 0, 0, 0);
            #pragma unroll
            for (int r = 0; r < 4; r++) {
                const int orow = mt * 16 + g * 4 + r;
                T[orow * 72 + col] = (_Float16)fmaxf(D[r], 0.f);
            }
        }
    }
    asm volatile("s_waitcnt lgkmcnt(0)" ::: "memory");

    // ---- layer 2: K=64, N=32, relu ----
    #pragma unroll
    for (int mt = 0; mt < 2; mt++) {
        const int arow = mt * 16 + cl;
        v8h A0 = *(const v8h*)(T + arow * 72 +      8 * g);
        v8h A1 = *(const v8h*)(T + arow * 72 + 32 + 8 * g);
        #pragma unroll
        for (int nt = 0; nt < 2; nt++) {
            const int col = cl + 16 * nt;
            float bias = sb2[col];
            v4f D = { bias, bias, bias, bias };
            v8h B0 = *(const v8h*)(&sW2t[col * 72 +      8 * g]);
            v8h B1 = *(const v8h*)(&sW2t[col * 72 + 32 + 8 * g]);
            D = __builtin_amdgcn_mfma_f32_16x16x32_f16(A0, B0, D, 0, 0, 0);
            D = __builtin_amdgcn_mfma_f32_16x16x32_f16(A1, B1, D, 0, 0, 0);
            #pragma unroll
            for (int r = 0; r < 4; r++) {
                const int orow = mt * 16 + g * 4 + r;
                T[orow * 72 + col] = (_Float16)fmaxf(D[r], 0.f);
            }
        }
    }
    asm volatile("s_waitcnt lgkmcnt(0)" ::: "memory");

    // ---- layer 3: K=32, N=64, sigmoid ----
    #pragma unroll
    for (int mt = 0; mt < 2; mt++) {
        const int arow = mt * 16 + cl;
        v8h A0 = *(const v8h*)(T + arow * 72 + 8 * g);
        #pragma unroll
        for (int nt = 0; nt < 4; nt++) {
            const int col = cl + 16 * nt;
            float bias = sb3[col];
            v4f D = { bias, bias, bias, bias };
            v8h B0 = *(const v8h*)(&sW3t[col * 40 + 8 * g]);
            D = __builtin_amdgcn_mfma_f32_16x16x32_f16(A0, B0, D, 0, 0, 0);
            #pragma unroll
            for (int r = 0; r < 4; r++) {
                const int orow = mt * 16 + g * 4 + r;
                float s = 1.0f / (1.0f + __expf(-D[r]));
                T[orow * 72 + col] = (_Float16)s;
            }
        }
    }
    asm volatile("s_waitcnt lgkmcnt(0)" ::: "memory");

    // ---- coalesced readout: LDS -> global h16[e][64] ----
    {
        const int row = ln >> 1, half = ln & 1;
        const _Float16* rp = T + row * 72 + half * 32;
        v8h s0 = *(const v8h*)(rp + 0);
        v8h s1 = *(const v8h*)(rp + 8);
        v8h s2 = *(const v8h*)(rp + 16);
        v8h s3 = *(const v8h*)(rp + 24);
        _Float16* gp = h16 + ((size_t)hb * E_ + e0 + row) * EOUT + half * 32;
        *(v8h*)(gp + 0)  = s0;
        *(v8h*)(gp + 8)  = s1;
        *(v8h*)(gp + 16) = s2;
        *(v8h*)(gp + 24) = s3;
    }
}

// ---------------- pass B: 16B/lane gather + LDS accumulate + node MLP ----------------
// 8 lanes per entry, each lane loads dwordx4 (8 f16) of the 128 B h-row.
// Two entry-groups (16 entries) in flight per wave iteration.

__global__ __launch_bounds__(256) void aggregate_kernel(
    const _Float16* __restrict__ h16,   // [grid.y][E][64]
    const float* __restrict__ lp,       // [B][N]
    const unsigned* __restrict__ entries,
    const int* __restrict__ offsets,
    const float* __restrict__ W4, const float* __restrict__ b4,
    const float* __restrict__ W5, const float* __restrict__ b5,
    float* __restrict__ out,            // [B][N]
    int bbase)
{
    __shared__ float sagg[CH2][68];
    __shared__ float sW4[(EOUT + 1) * NHID];
    __shared__ float sb4[NHID];
    __shared__ float sW5[NHID];
    __shared__ float sb5v;

    const int tid = threadIdx.x;
    const int c   = blockIdx.x;
    const int hb  = blockIdx.y;
    const int b   = bbase + hb;
    const int node0  = c * CH2;
    const int nvalid = min(CH2, N_ - node0);

    for (int i = tid; i < (EOUT + 1) * NHID; i += 256) sW4[i] = W4[i];
    if (tid < NHID) { sb4[tid] = b4[tid]; sW5[tid] = W5[tid]; }
    if (tid == 0) sb5v = b5[0];
    {
        float* sa = &sagg[0][0];
        for (int i = tid; i < CH2 * 68; i += 256) sa[i] = 0.f;
    }
    __syncthreads();

    const int beg = offsets[c], end = offsets[c + 1];
    const int wv = tid >> 6, ln = tid & 63;
    const int eslot = ln >> 3;          // entry slot within group (0..7)
    const int ch8   = ln & 7;           // 8-channel chunk (0..7)
    const _Float16* hbp = h16 + (size_t)hb * E_ * EOUT;

    for (int it = beg + wv * 16; it < end; it += 64) {
        const int i0 = it + eslot, i1 = i0 + 8;
        const bool v0 = (i0 < end), v1 = (i1 < end);
        unsigned e0 = v0 ? entries[i0] : 0u;
        unsigned e1 = v1 ? entries[i1] : 0u;
        v8h h0, h1;
        if (v0) h0 = *(const v8h*)(hbp + (size_t)(e0 & 0x7FFFFu) * EOUT + ch8 * 8);
        if (v1) h1 = *(const v8h*)(hbp + (size_t)(e1 & 0x7FFFFu) * EOUT + ch8 * 8);
        if (v0) {
            const float sgn = ((e0 >> 19) & 1u) ? -1.f : 1.f;
            float* bp = &sagg[(e0 >> 20) & 31u][ch8 * 8];
            #pragma unroll
            for (int j = 0; j < 8; j++) atomicAdd(bp + j, sgn * (float)h0[j]);
        }
        if (v1) {
            const float sgn = ((e1 >> 19) & 1u) ? -1.f : 1.f;
            float* bp = &sagg[(e1 >> 20) & 31u][ch8 * 8];
            #pragma unroll
            for (int j = 0; j < 8; j++) atomicAdd(bp + j, sgn * (float)h1[j]);
        }
    }
    __syncthreads();

    // ---- fused node MLP: 65 -> 12 -> 1 ----
    if (tid < nvalid) {
        float nh[NHID];
        #pragma unroll
        for (int j = 0; j < NHID; j++) nh[j] = sb4[j];
        const float* ar = &sagg[tid][0];
        #pragma unroll
        for (int k = 0; k < EOUT; k++) {
            float v = ar[k];
            const float* wr = sW4 + k * NHID;
            #pragma unroll
            for (int j = 0; j < NHID; j++) nh[j] = fmaf(v, wr[j], nh[j]);
        }
        {
            float v = lp[(size_t)b * N_ + node0 + tid];
            const float* wr = sW4 + EOUT * NHID;
            #pragma unroll
            for (int j = 0; j < NHID; j++) nh[j] = fmaf(v, wr[j], nh[j]);
        }
        float acc = sb5v;
        #pragma unroll
        for (int j = 0; j < NHID; j++) acc = fmaf(fmaxf(nh[j], 0.f), sW5[j], acc);
        out[(size_t)b * N_ + node0 + tid] = 1.0f / (1.0f + __expf(-acc));
    }
}

// ---------------- launch ----------------

extern "C" void kernel_launch(void* const* d_in, const int* in_sizes, int n_in,
                              void* d_out, int out_size, void* d_ws, size_t ws_size,
                              hipStream_t stream)
{
    const float* nf   = (const float*)d_in[0];
    const float* ew   = (const float*)d_in[1];
    const float* lp   = (const float*)d_in[2];
    const int*   esrc = (const int*)d_in[3];
    const int*   etgt = (const int*)d_in[4];
    const float* W1 = (const float*)d_in[5],  *b1 = (const float*)d_in[6];
    const float* W2 = (const float*)d_in[7],  *b2 = (const float*)d_in[8];
    const float* W3 = (const float*)d_in[9],  *b3 = (const float*)d_in[10];
    const float* W4 = (const float*)d_in[11], *b4 = (const float*)d_in[12];
    const float* W5 = (const float*)d_in[13], *b5 = (const float*)d_in[14];

    float* out = (float*)d_out;
    char*  ws  = (char*)d_ws;

    const size_t H_OFF      = 4u << 20;
    const size_t H_BATCH    = (size_t)E_ * EOUT * sizeof(_Float16);
    const size_t NEED_FULL  = H_OFF + (size_t)B_ * H_BATCH;
    const size_t NEED_BATCH = H_OFF + H_BATCH;

    int*      counts  = (int*)(ws + 0);
    int*      offsets = (int*)(ws + 2048);
    int*      cursors = (int*)(ws + 4096);
    unsigned* entries = (unsigned*)(ws + 8192);
    _Float16* h16     = (_Float16*)(ws + H_OFF);

    hipMemsetAsync(counts, 0, 2048, stream);
    hist_kernel<<<E_ / 256, 256, 0, stream>>>(esrc, etgt, counts);
    scan_kernel<<<1, 64, 0, stream>>>(counts, offsets, cursors);
    fill_kernel<<<E_ / 256, 256, 0, stream>>>(esrc, etgt, cursors, entries);

    if (ws_size >= NEED_FULL) {
        dim3 ga(E_ / 128, B_);
        edge_mfma_kernel<<<ga, 256, 0, stream>>>(nf, ew, esrc, etgt,
                                                 W1, b1, W2, b2, W3, b3, h16, 0);
        dim3 gb(NCHUNK2, B_);
        aggregate_kernel<<<gb, 256, 0, stream>>>(h16, lp, entries, offsets,
                                                 W4, b4, W5, b5, out, 0);
    } else if (ws_size >= NEED_BATCH) {
        for (int b = 0; b < B_; b++) {
            dim3 ga(E_ / 128, 1);
            edge_mfma_kernel<<<ga, 256, 0, stream>>>(nf, ew, esrc, etgt,
                                                     W1, b1, W2, b2, W3, b3, h16, b);
            dim3 gb(NCHUNK2, 1);
            aggregate_kernel<<<gb, 256, 0, stream>>>(h16, lp, entries, offsets,
                                                     W4, b4, W5, b5, out, b);
        }
    }
}

// Round 5
// 1020.129 us; speedup vs baseline: 3.6321x; 1.2456x over previous
//
#include <hip/hip_runtime.h>
#include <cstdint>
#include <cstddef>

#define B_      4
#define N_      10000
#define E_      320000
#define FN_     16
#define EOUT    64
#define NHID    12
#define CH      32
#define NCHUNK  313   // ceil(10000/32)
#define HB      250   // hist/fill blocks
#define EPB     1280  // edges per hist/fill block (250*1280 = 320000)

typedef _Float16 v8h __attribute__((ext_vector_type(8)));
typedef float    v4f __attribute__((ext_vector_type(4)));

// ws layout (bytes):
//   [0,    1252)  counts[313]
//   [2048, 3304)  offsets[314]
//   [4096, 5348)  cursors[313]
//   [8192, +5.12M) entries[2*E] uint2: {e | isSrc<<19 | own_local<<20, other_node}

// ---------------- prepass 1: per-chunk histogram (LDS-combined) ----------------

__global__ __launch_bounds__(256) void hist_kernel(
    const int* __restrict__ esrc, const int* __restrict__ etgt,
    int* __restrict__ counts)
{
    __shared__ int hc[NCHUNK];
    const int tid = threadIdx.x;
    for (int i = tid; i < NCHUNK; i += 256) hc[i] = 0;
    __syncthreads();
    const int e0 = blockIdx.x * EPB;
    #pragma unroll
    for (int k = 0; k < EPB / 256; k++) {
        const int e = e0 + k * 256 + tid;
        atomicAdd(&hc[esrc[e] >> 5], 1);
        atomicAdd(&hc[etgt[e] >> 5], 1);
    }
    __syncthreads();
    for (int i = tid; i < NCHUNK; i += 256)
        if (hc[i]) atomicAdd(&counts[i], hc[i]);
}

// ---------------- prepass 2: one-block parallel exclusive scan ----------------

__global__ __launch_bounds__(512) void scan_kernel(
    const int* __restrict__ counts,
    int* __restrict__ offsets, int* __restrict__ cursors)
{
    __shared__ int s[512];
    const int tid = threadIdx.x;
    s[tid] = (tid < NCHUNK) ? counts[tid] : 0;
    __syncthreads();
    #pragma unroll
    for (int off = 1; off < 512; off <<= 1) {
        int v = (tid >= off) ? s[tid - off] : 0;
        __syncthreads();
        s[tid] += v;
        __syncthreads();
    }
    // s is now inclusive scan
    if (tid < NCHUNK) {
        int excl = (tid == 0) ? 0 : s[tid - 1];
        offsets[tid] = excl;
        cursors[tid] = excl;
    }
    if (tid == 0) offsets[NCHUNK] = s[NCHUNK - 1];
}

// ---------------- prepass 3: fill entry lists (block-reserve-combined) ----------------

__global__ __launch_bounds__(256) void fill_kernel(
    const int* __restrict__ esrc, const int* __restrict__ etgt,
    int* __restrict__ cursors, uint2* __restrict__ entries)
{
    __shared__ int hc[NCHUNK];
    __shared__ int base_[NCHUNK];
    const int tid = threadIdx.x;
    for (int i = tid; i < NCHUNK; i += 256) hc[i] = 0;
    __syncthreads();
    const int e0 = blockIdx.x * EPB;
    #pragma unroll
    for (int k = 0; k < EPB / 256; k++) {
        const int e = e0 + k * 256 + tid;
        atomicAdd(&hc[esrc[e] >> 5], 1);
        atomicAdd(&hc[etgt[e] >> 5], 1);
    }
    __syncthreads();
    for (int i = tid; i < NCHUNK; i += 256) {
        if (hc[i] > 0) {
            base_[i] = atomicAdd(&cursors[i], hc[i]);  // one reservation per chunk per block
            hc[i] = 0;                                  // reuse as local cursor
        }
    }
    __syncthreads();
    #pragma unroll
    for (int k = 0; k < EPB / 256; k++) {
        const int e = e0 + k * 256 + tid;
        const int s = esrc[e], t = etgt[e];
        const int cs = s >> 5, ct = t >> 5;
        int p = base_[cs] + atomicAdd(&hc[cs], 1);
        entries[p] = make_uint2((unsigned)e | (1u << 19) | ((unsigned)(s & 31) << 20), (unsigned)t);
        p = base_[ct] + atomicAdd(&hc[ct], 1);
        entries[p] = make_uint2((unsigned)e | ((unsigned)(t & 31) << 20), (unsigned)s);
    }
}

// ---------------- fused chunk kernel ----------------
// One block per (chunk of 32 nodes, batch). Per wave: 32-entry tiles.
// Stage e_in in LDS [32][72] f16 -> 3-layer MFMA MLP (round-4 engine, proven)
// -> layer-3 D-frags: sigmoid, sign, masked ds_add_f32 into sagg[32][68]
// -> fused node MLP (65 -> 12 -> 1) -> out. No h materialization, no global atomics.

__global__ __launch_bounds__(256, 3) void chunk_kernel(
    const float* __restrict__ nf,      // [B][N][16]
    const float* __restrict__ ew,      // [B][E]
    const float* __restrict__ lp,      // [B][N]
    const uint2* __restrict__ entries,
    const int*   __restrict__ offsets,
    const float* __restrict__ W1, const float* __restrict__ b1,
    const float* __restrict__ W2, const float* __restrict__ b2,
    const float* __restrict__ W3, const float* __restrict__ b3,
    const float* __restrict__ W4, const float* __restrict__ b4,
    const float* __restrict__ W5, const float* __restrict__ b5,
    float* __restrict__ out)           // [B][N]
{
    __shared__ __align__(16) _Float16 sT[4][32 * 72];   // 18432 B
    __shared__ __align__(16) _Float16 sW1t[64 * 72];    // 9216 B  [n][k]
    __shared__ __align__(16) _Float16 sW2t[32 * 72];    // 4608 B
    __shared__ __align__(16) _Float16 sW3t[64 * 40];    // 5120 B
    __shared__ float sb1[64], sb2[32], sb3[64];
    __shared__ uint2    sent[4][32];                    // entry tile per wave
    __shared__ unsigned sot[4][32];                     // own | isSrc<<6 | valid<<7
    __shared__ float sagg[CH][68];                      // 8704 B
    __shared__ float sW4[(EOUT + 1) * NHID];            // 3120 B
    __shared__ float sb4[NHID];
    __shared__ float sW5[NHID];
    __shared__ float sb5v;

    const int tid   = threadIdx.x;
    const int c     = blockIdx.x;
    const int b     = blockIdx.y;
    const int node0 = c * CH;
    const int nvalid = min(CH, N_ - node0);

    // ---- stage transposed, zero-padded weights (verbatim round-4) ----
    {
        const int n = tid & 63, kq = tid >> 6;
        const int k0 = kq * 16;
        v8h a, cc;
        #pragma unroll
        for (int j = 0; j < 8; j++) {
            int k = k0 + j;      a[j]  = (k  < 33) ? (_Float16)W1[k  * 64 + n] : (_Float16)0.f;
            int k2 = k0 + 8 + j; cc[j] = (k2 < 33) ? (_Float16)W1[k2 * 64 + n] : (_Float16)0.f;
        }
        *(v8h*)&sW1t[n * 72 + k0]     = a;
        *(v8h*)&sW1t[n * 72 + k0 + 8] = cc;
    }
    {
        const int n = tid & 31, kq = tid >> 5;
        const int k0 = kq * 8;
        v8h a;
        #pragma unroll
        for (int j = 0; j < 8; j++) a[j] = (_Float16)W2[(k0 + j) * 32 + n];
        *(v8h*)&sW2t[n * 72 + k0] = a;
    }
    {
        const int n = tid & 63, kh = tid >> 6;
        const int k0 = kh * 8;
        v8h a;
        #pragma unroll
        for (int j = 0; j < 8; j++) a[j] = (_Float16)W3[(k0 + j) * 64 + n];
        *(v8h*)&sW3t[n * 40 + k0] = a;
    }
    if (tid < 64) sb1[tid] = b1[tid];
    if (tid < 32) sb2[tid] = b2[tid];
    if (tid < 64) sb3[tid] = b3[tid];
    for (int i = tid; i < (EOUT + 1) * NHID; i += 256) sW4[i] = W4[i];
    if (tid < NHID) { sb4[tid] = b4[tid]; sW5[tid] = W5[tid]; }
    if (tid == 0) sb5v = b5[0];
    {
        float* sa = &sagg[0][0];
        for (int i = tid; i < CH * 68; i += 256) sa[i] = 0.f;
    }
    __syncthreads();

    const int wv = tid >> 6, ln = tid & 63;
    const int g  = ln >> 4;            // lane k-group 0..3
    const int cl = ln & 15;            // lane col/row index
    _Float16* T = &sT[wv][0];
    const float* nfB = nf + (size_t)b * N_ * FN_;
    const float* ewB = ew + (size_t)b * E_;

    const int beg = offsets[c], end = offsets[c + 1];

    for (int base = beg + wv * 32; base < end; base += 128) {
        // ---- 1) load entry tile (lanes 0..31, coalesced 8 B) ----
        if (ln < 32) {
            const int idx = base + ln;
            const bool valid = (idx < end);
            uint2 ent = valid ? entries[idx] : make_uint2(0u, 0u);
            sent[wv][ln] = ent;
            sot[wv][ln]  = valid ? (((ent.x >> 20) & 31u) | (((ent.x >> 19) & 1u) << 6) | 0x80u) : 0u;
        }
        asm volatile("s_waitcnt lgkmcnt(0)" ::: "memory");

        // ---- 2) stage e_in tile (lane = half-entry) ----
        {
            const int el   = ln >> 1;
            const int half = ln & 1;
            const uint2 ent = sent[wv][el];
            const int e     = (int)(ent.x & 0x7FFFFu);
            const int isSrc = (int)((ent.x >> 19) & 1u);
            const int own_g = node0 + (int)((ent.x >> 20) & 31u);
            const int other = (int)ent.y;
            // position 0 holds src features, position 1 holds tgt features
            const int node  = (half == 0) ? (isSrc ? own_g : other)
                                          : (isSrc ? other : own_g);
            const float4* pn = (const float4*)(nfB + (size_t)node * FN_);
            float4 f0 = pn[0], f1 = pn[1], f2 = pn[2], f3 = pn[3];
            v8h c0 = { (_Float16)f0.x, (_Float16)f0.y, (_Float16)f0.z, (_Float16)f0.w,
                       (_Float16)f1.x, (_Float16)f1.y, (_Float16)f1.z, (_Float16)f1.w };
            v8h c1 = { (_Float16)f2.x, (_Float16)f2.y, (_Float16)f2.z, (_Float16)f2.w,
                       (_Float16)f3.x, (_Float16)f3.y, (_Float16)f3.z, (_Float16)f3.w };
            _Float16* rp = T + el * 72;
            *(v8h*)(rp + half * 16)     = c0;
            *(v8h*)(rp + half * 16 + 8) = c1;
            v8h z = { (_Float16)0.f, (_Float16)0.f, (_Float16)0.f, (_Float16)0.f,
                      (_Float16)0.f, (_Float16)0.f, (_Float16)0.f, (_Float16)0.f };
            if (half == 0) {
                float w = ewB[e];
                v8h cw = z; cw[0] = (_Float16)w;
                *(v8h*)(rp + 32) = cw;          // k=32 edge weight, k33..39 zero
            } else {
                *(v8h*)(rp + 40) = z;
                *(v8h*)(rp + 48) = z;
                *(v8h*)(rp + 56) = z;
            }
        }
        asm volatile("s_waitcnt lgkmcnt(0)" ::: "memory");

        // ---- 3) layer 1: K=64 (padded), N=64, relu ----
        #pragma unroll
        for (int mt = 0; mt < 2; mt++) {
            const int arow = mt * 16 + cl;
            v8h A0 = *(const v8h*)(T + arow * 72 +      8 * g);
            v8h A1 = *(const v8h*)(T + arow * 72 + 32 + 8 * g);
            #pragma unroll
            for (int nt = 0; nt < 4; nt++) {
                const int col = cl + 16 * nt;
                float bias = sb1[col];
                v4f D = { bias, bias, bias, bias };
                v8h B0 = *(const v8h*)(&sW1t[col * 72 +      8 * g]);
                v8h B1 = *(const v8h*)(&sW1t[col * 72 + 32 + 8 * g]);
                D = __builtin_amdgcn_mfma_f32_16x16x32_f16(A0, B0, D, 0, 0, 0);
                D = __builtin_amdgcn_mfma_f32_16x16x32_f16(A1, B1, D, 0, 0, 0);
                #pragma unroll
                for (int r = 0; r < 4; r++) {
                    const int orow = mt * 16 + g * 4 + r;
                    T[orow * 72 + col] = (_Float16)fmaxf(D[r], 0.f);
                }
            }
        }
        asm volatile("s_waitcnt lgkmcnt(0)" ::: "memory");

        // ---- 4) layer 2: K=64, N=32, relu ----
        #pragma unroll
        for (int mt = 0; mt < 2; mt++) {
            const int arow = mt * 16 + cl;
            v8h A0 = *(const v8h*)(T + arow * 72 +      8 * g);
            v8h A1 = *(const v8h*)(T + arow * 72 + 32 + 8 * g);
            #pragma unroll
            for (int nt = 0; nt < 2; nt++) {
                const int col = cl + 16 * nt;
                float bias = sb2[col];
                v4f D = { bias, bias, bias, bias };
                v8h B0 = *(const v8h*)(&sW2t[col * 72 +      8 * g]);
                v8h B1 = *(const v8h*)(&sW2t[col * 72 + 32 + 8 * g]);
                D = __builtin_amdgcn_mfma_f32_16x16x32_f16(A0, B0, D, 0, 0, 0);
                D = __builtin_amdgcn_mfma_f32_16x16x32_f16(A1, B1, D, 0, 0, 0);
                #pragma unroll
                for (int r = 0; r < 4; r++) {
                    const int orow = mt * 16 + g * 4 + r;
                    T[orow * 72 + col] = (_Float16)fmaxf(D[r], 0.f);
                }
            }
        }
        asm volatile("s_waitcnt lgkmcnt(0)" ::: "memory");

        // ---- 5) layer 3: K=32, N=64, sigmoid, signed masked LDS scatter ----
        #pragma unroll
        for (int mt = 0; mt < 2; mt++) {
            const int arow = mt * 16 + cl;
            v8h A0 = *(const v8h*)(T + arow * 72 + 8 * g);
            unsigned so[4];
            #pragma unroll
            for (int r = 0; r < 4; r++) so[r] = sot[wv][mt * 16 + g * 4 + r];
            #pragma unroll
            for (int nt = 0; nt < 4; nt++) {
                const int col = cl + 16 * nt;
                float bias = sb3[col];
                v4f D = { bias, bias, bias, bias };
                v8h B0 = *(const v8h*)(&sW3t[col * 40 + 8 * g]);
                D = __builtin_amdgcn_mfma_f32_16x16x32_f16(A0, B0, D, 0, 0, 0);
                #pragma unroll
                for (int r = 0; r < 4; r++) {
                    const unsigned m = so[r];
                    if (m & 0x80u) {
                        float s = 1.0f / (1.0f + __expf(-D[r]));
                        if (m & 0x40u) s = -s;          // own == src -> subtract
                        atomicAdd(&sagg[m & 31u][col], s);   // ds_add_f32
                    }
                }
            }
        }
        asm volatile("s_waitcnt lgkmcnt(0)" ::: "memory");
    }

    __syncthreads();

    // ---- fused node MLP: 65 -> 12 -> 1 ----
    if (tid < nvalid) {
        float nh[NHID];
        #pragma unroll
        for (int j = 0; j < NHID; j++) nh[j] = sb4[j];
        const float* ar = &sagg[tid][0];
        #pragma unroll
        for (int k = 0; k < EOUT; k++) {
            float v = ar[k];
            const float* wr = sW4 + k * NHID;
            #pragma unroll
            for (int j = 0; j < NHID; j++) nh[j] = fmaf(v, wr[j], nh[j]);
        }
        {
            float v = lp[(size_t)b * N_ + node0 + tid];
            const float* wr = sW4 + EOUT * NHID;
            #pragma unroll
            for (int j = 0; j < NHID; j++) nh[j] = fmaf(v, wr[j], nh[j]);
        }
        float acc = sb5v;
        #pragma unroll
        for (int j = 0; j < NHID; j++) acc = fmaf(fmaxf(nh[j], 0.f), sW5[j], acc);
        out[(size_t)b * N_ + node0 + tid] = 1.0f / (1.0f + __expf(-acc));
    }
}

// ---------------- launch ----------------

extern "C" void kernel_launch(void* const* d_in, const int* in_sizes, int n_in,
                              void* d_out, int out_size, void* d_ws, size_t ws_size,
                              hipStream_t stream)
{
    const float* nf   = (const float*)d_in[0];
    const float* ew   = (const float*)d_in[1];
    const float* lp   = (const float*)d_in[2];
    const int*   esrc = (const int*)d_in[3];
    const int*   etgt = (const int*)d_in[4];
    const float* W1 = (const float*)d_in[5],  *b1 = (const float*)d_in[6];
    const float* W2 = (const float*)d_in[7],  *b2 = (const float*)d_in[8];
    const float* W3 = (const float*)d_in[9],  *b3 = (const float*)d_in[10];
    const float* W4 = (const float*)d_in[11], *b4 = (const float*)d_in[12];
    const float* W5 = (const float*)d_in[13], *b5 = (const float*)d_in[14];

    float* out = (float*)d_out;
    char*  ws  = (char*)d_ws;

    int*   counts  = (int*)(ws + 0);
    int*   offsets = (int*)(ws + 2048);
    int*   cursors = (int*)(ws + 4096);
    uint2* entries = (uint2*)(ws + 8192);

    hipMemsetAsync(counts, 0, 2048, stream);
    hist_kernel<<<HB, 256, 0, stream>>>(esrc, etgt, counts);
    scan_kernel<<<1, 512, 0, stream>>>(counts, offsets, cursors);
    fill_kernel<<<HB, 256, 0, stream>>>(esrc, etgt, cursors, entries);

    dim3 cg(NCHUNK, B_);
    chunk_kernel<<<cg, 256, 0, stream>>>(nf, ew, lp, entries, offsets,
                                         W1, b1, W2, b2, W3, b3,
                                         W4, b4, W5, b5, out);
}

// Round 8
// 943.186 us; speedup vs baseline: 3.9284x; 1.0816x over previous
//
#include <hip/hip_runtime.h>
#include <cstdint>
#include <cstddef>

#define B_      4
#define N_      10000
#define E_      320000
#define FN_     16
#define EOUT    64
#define NHID    12
#define CH      32
#define NCHUNK  313   // ceil(10000/32)
#define HB      250
#define EPB     1280
#define SENTX   (32u << 20)

typedef _Float16 v8h __attribute__((ext_vector_type(8)));
typedef float    v4f __attribute__((ext_vector_type(4)));

// RTN pack of two floats into packed-f16 dword (matches rounds 4/5 numerics)
__device__ __forceinline__ uint32_t pkh(float a, float b) {
    _Float16 lo = (_Float16)a, hi = (_Float16)b;
    uint32_t ul = (uint32_t)__builtin_bit_cast(uint16_t, lo);
    uint32_t uh = (uint32_t)__builtin_bit_cast(uint16_t, hi);
    return ul | (uh << 16);
}
__device__ __forceinline__ v8h mkv8h(uint32_t a, uint32_t b, uint32_t c, uint32_t d) {
    uint4 t = make_uint4(a, b, c, d);
    return __builtin_bit_cast(v8h, t);
}

// ---------------- prepasses (proven, unchanged) ----------------

__global__ __launch_bounds__(256) void hist_kernel(
    const int* __restrict__ esrc, const int* __restrict__ etgt,
    int* __restrict__ counts)
{
    __shared__ int hc[NCHUNK];
    const int tid = threadIdx.x;
    for (int i = tid; i < NCHUNK; i += 256) hc[i] = 0;
    __syncthreads();
    const int e0 = blockIdx.x * EPB;
    #pragma unroll
    for (int k = 0; k < EPB / 256; k++) {
        const int e = e0 + k * 256 + tid;
        atomicAdd(&hc[esrc[e] >> 5], 1);
        atomicAdd(&hc[etgt[e] >> 5], 1);
    }
    __syncthreads();
    for (int i = tid; i < NCHUNK; i += 256)
        if (hc[i]) atomicAdd(&counts[i], hc[i]);
}

__global__ __launch_bounds__(512) void scan_kernel(
    const int* __restrict__ counts,
    int* __restrict__ offsets, int* __restrict__ cursors)
{
    __shared__ int s[512];
    const int tid = threadIdx.x;
    s[tid] = (tid < NCHUNK) ? counts[tid] : 0;
    __syncthreads();
    #pragma unroll
    for (int off = 1; off < 512; off <<= 1) {
        int v = (tid >= off) ? s[tid - off] : 0;
        __syncthreads();
        s[tid] += v;
        __syncthreads();
    }
    if (tid < NCHUNK) {
        int excl = (tid == 0) ? 0 : s[tid - 1];
        offsets[tid] = excl;
        cursors[tid] = excl;
    }
    if (tid == 0) offsets[NCHUNK] = s[NCHUNK - 1];
}

__global__ __launch_bounds__(256) void fill_kernel(
    const int* __restrict__ esrc, const int* __restrict__ etgt,
    int* __restrict__ cursors, uint2* __restrict__ entries)
{
    __shared__ int hc[NCHUNK];
    __shared__ int base_[NCHUNK];
    const int tid = threadIdx.x;
    for (int i = tid; i < NCHUNK; i += 256) hc[i] = 0;
    __syncthreads();
    const int e0 = blockIdx.x * EPB;
    #pragma unroll
    for (int k = 0; k < EPB / 256; k++) {
        const int e = e0 + k * 256 + tid;
        atomicAdd(&hc[esrc[e] >> 5], 1);
        atomicAdd(&hc[etgt[e] >> 5], 1);
    }
    __syncthreads();
    for (int i = tid; i < NCHUNK; i += 256) {
        if (hc[i] > 0) {
            base_[i] = atomicAdd(&cursors[i], hc[i]);
            hc[i] = 0;
        }
    }
    __syncthreads();
    #pragma unroll
    for (int k = 0; k < EPB / 256; k++) {
        const int e = e0 + k * 256 + tid;
        const int s = esrc[e], t = etgt[e];
        const int cs = s >> 5, ct = t >> 5;
        int p = base_[cs] + atomicAdd(&hc[cs], 1);
        entries[p] = make_uint2((unsigned)e | (1u << 19) | ((unsigned)(s & 31) << 20), (unsigned)t);
        p = base_[ct] + atomicAdd(&hc[ct], 1);
        entries[p] = make_uint2((unsigned)e | ((unsigned)(t & 31) << 20), (unsigned)s);
    }
}

// ---------------- fused chunk kernel: register-resident swapped MFMA ----------------
// A-operand = W^T (register-resident), B-operand = 16-edge tile gathered
// straight from global. Layer transitions: pack h to f16 in-register, then
// ds_bpermute BOTH mt-candidate registers and select on the DEST lane
// (bpermute src is the SOURCE lane's value — selection must be post-permute).

__device__ __forceinline__ void decode_entry(uint2 ent, int node0, int g,
                                             int& node, int& own, float& sgn, int& eidx)
{
    eidx = (int)(ent.x & 0x7FFFFu);
    const int isSrc = (int)((ent.x >> 19) & 1u);
    own = (int)((ent.x >> 20) & 63u);            // 0..31, sentinel 32
    const int own_g = min(node0 + own, N_ - 1);
    const int other = (int)ent.y;
    const int srcn = isSrc ? own_g : other;
    const int tgtn = isSrc ? other : own_g;
    node = (g < 2) ? srcn : tgtn;
    sgn = isSrc ? -1.f : 1.f;
}

__global__ __launch_bounds__(256, 2) void chunk_kernel(
    const float* __restrict__ nf,      // [B][N][16]
    const float* __restrict__ ew,      // [B][E]
    const float* __restrict__ lp,      // [B][N]
    const uint2* __restrict__ entries,
    const int*   __restrict__ offsets,
    const float* __restrict__ W1, const float* __restrict__ b1,
    const float* __restrict__ W2, const float* __restrict__ b2,
    const float* __restrict__ W3, const float* __restrict__ b3,
    const float* __restrict__ W4, const float* __restrict__ b4,
    const float* __restrict__ W5, const float* __restrict__ b5,
    float* __restrict__ out)           // [B][N]
{
    __shared__ float sagg[CH + 1][68];           // row 32 = dump row for invalid lanes
    __shared__ float sW4[(EOUT + 1) * NHID];
    __shared__ float sb4[NHID];
    __shared__ float sW5[NHID];
    __shared__ float sb5v;

    const int tid   = threadIdx.x;
    const int c     = blockIdx.x;
    const int b     = blockIdx.y;
    const int node0 = c * CH;
    const int nvalid = min(CH, N_ - node0);

    for (int i = tid; i < (EOUT + 1) * NHID; i += 256) sW4[i] = W4[i];
    if (tid < NHID) { sb4[tid] = b4[tid]; sW5[tid] = W5[tid]; }
    if (tid == 0) sb5v = b5[0];
    {
        float* sa = &sagg[0][0];
        for (int i = tid; i < (CH + 1) * 68; i += 256) sa[i] = 0.f;
    }

    const int wv = tid >> 6, ln = tid & 63;
    const int g  = ln >> 4;            // k-group 0..3
    const int cl = ln & 15;            // edge-in-tile / out-channel-in-tile

    // ---- per-wave register weight fragments (A-operand = W^T) ----
    v8h A0w1[4], A1w1[4], A0w2[2], A1w2[2], A0w3[4];
    #pragma unroll
    for (int mt = 0; mt < 4; mt++) {
        const int och = 16 * mt + cl;
        float f[8];
        #pragma unroll
        for (int j = 0; j < 8; j++) f[j] = W1[(8 * g + j) * 64 + och];
        A0w1[mt] = mkv8h(pkh(f[0],f[1]), pkh(f[2],f[3]), pkh(f[4],f[5]), pkh(f[6],f[7]));
        const float wr = W1[32 * 64 + och];      // k=32: edge-weight row
        const float bb = b1[och];                // k=33: bias (B supplies 1.0)
        A1w1[mt] = (g == 0) ? mkv8h(pkh(wr, bb), 0u, 0u, 0u) : mkv8h(0u, 0u, 0u, 0u);
    }
    #pragma unroll
    for (int mt = 0; mt < 2; mt++) {
        const int och = 16 * mt + cl;
        float f[8];
        #pragma unroll
        for (int j = 0; j < 8; j++) f[j] = W2[(8 * g + j) * 32 + och];
        A0w2[mt] = mkv8h(pkh(f[0],f[1]), pkh(f[2],f[3]), pkh(f[4],f[5]), pkh(f[6],f[7]));
        #pragma unroll
        for (int j = 0; j < 8; j++) f[j] = W2[(32 + 8 * g + j) * 32 + och];
        A1w2[mt] = mkv8h(pkh(f[0],f[1]), pkh(f[2],f[3]), pkh(f[4],f[5]), pkh(f[6],f[7]));
    }
    #pragma unroll
    for (int mt = 0; mt < 4; mt++) {
        const int och = 16 * mt + cl;
        float f[8];
        #pragma unroll
        for (int j = 0; j < 8; j++) f[j] = W3[(8 * g + j) * 64 + och];
        A0w3[mt] = mkv8h(pkh(f[0],f[1]), pkh(f[2],f[3]), pkh(f[4],f[5]), pkh(f[6],f[7]));
    }
    float b2v[2][4], b3v[4][4];
    #pragma unroll
    for (int mt = 0; mt < 2; mt++)
        #pragma unroll
        for (int r = 0; r < 4; r++) b2v[mt][r] = b2[16 * mt + 4 * g + r];
    #pragma unroll
    for (int mt = 0; mt < 4; mt++)
        #pragma unroll
        for (int r = 0; r < 4; r++) b3v[mt][r] = b3[16 * mt + 4 * g + r];

    __syncthreads();   // sagg zeroed, node-MLP weights staged

    const int beg = offsets[c], end = offsets[c + 1];
    const int a1 = (32 * (g & 1) + cl) * 4;      // source lane g'' = 2*(g&1)
    const int a2 = a1 + 64;                      // source lane g'' = 2*(g&1)+1
    const bool glo = (g < 2);                    // dest-side mt select
    const float* nfB = nf + (size_t)b * N_ * FN_;
    const float* ewB = ew + (size_t)b * E_;

    int base = beg + wv * 16;

    // ---- prologue: tile 0 loads + tile 1 entries ----
    uint2 entn_raw = make_uint2(SENTX, 0u);
    int own_c = 32, e_c = 0, node_c = 0; float sgn_c = 1.f;
    float4 q0c = {0,0,0,0}, q1c = {0,0,0,0}; float wc = 0.f;
    if (base < end) {
        int idx = base + cl;
        uint2 ent = entries[min(idx, end - 1)];
        if (idx >= end) ent = make_uint2(SENTX, 0u);
        decode_entry(ent, node0, g, node_c, own_c, sgn_c, e_c);
        const float* p = nfB + (size_t)node_c * FN_ + (g & 1) * 8;
        q0c = *(const float4*)p; q1c = *(const float4*)(p + 4);
        wc = ewB[e_c];
        if (base + 64 < end) {
            idx = base + 64 + cl;
            entn_raw = entries[min(idx, end - 1)];
        }
    }

    #pragma unroll 1
    while (base < end) {
        const int nbase = base + 64;

        // ---- prefetch stage: decode next tile, issue its loads ----
        uint2 entn = entn_raw;
        { int idx = nbase + cl; if (idx >= end) entn = make_uint2(SENTX, 0u); }
        int own_n, e_n, node_n; float sgn_n;
        decode_entry(entn, node0, g, node_n, own_n, sgn_n, e_n);
        const float* pn = nfB + (size_t)node_n * FN_ + (g & 1) * 8;
        float4 q0n = *(const float4*)pn;
        float4 q1n = *(const float4*)(pn + 4);
        float  wn  = ewB[e_n];
        uint2 entnn = make_uint2(SENTX, 0u);
        if (nbase + 64 < end) {
            int idx = nbase + 64 + cl;
            entnn = entries[min(idx, end - 1)];
        }

        // ---- B-frags for current tile (e_in^T direct from registers) ----
        v8h B0 = mkv8h(pkh(q0c.x, q0c.y), pkh(q0c.z, q0c.w),
                       pkh(q1c.x, q1c.y), pkh(q1c.z, q1c.w));
        v8h B1 = mkv8h((g == 0) ? pkh(wc, 1.0f) : 0u, 0u, 0u, 0u);

        // ---- layer 1: 4 och-tiles, K=64 (bias folded), relu, pack ----
        uint32_t dA[4], dB[4];
        #pragma unroll
        for (int mt = 0; mt < 4; mt++) {
            v4f D = {0.f, 0.f, 0.f, 0.f};
            D = __builtin_amdgcn_mfma_f32_16x16x32_f16(A0w1[mt], B0, D, 0, 0, 0);
            D = __builtin_amdgcn_mfma_f32_16x16x32_f16(A1w1[mt], B1, D, 0, 0, 0);
            dA[mt] = pkh(fmaxf(D[0], 0.f), fmaxf(D[1], 0.f));
            dB[mt] = pkh(fmaxf(D[2], 0.f), fmaxf(D[3], 0.f));
        }

        // ---- transition 1: permute BOTH mt candidates, select on dest ----
        uint32_t pa1A0 = (uint32_t)__builtin_amdgcn_ds_bpermute(a1, (int)dA[0]);
        uint32_t pa1A1 = (uint32_t)__builtin_amdgcn_ds_bpermute(a1, (int)dA[1]);
        uint32_t pa1B0 = (uint32_t)__builtin_amdgcn_ds_bpermute(a1, (int)dB[0]);
        uint32_t pa1B1 = (uint32_t)__builtin_amdgcn_ds_bpermute(a1, (int)dB[1]);
        uint32_t pa2A0 = (uint32_t)__builtin_amdgcn_ds_bpermute(a2, (int)dA[0]);
        uint32_t pa2A1 = (uint32_t)__builtin_amdgcn_ds_bpermute(a2, (int)dA[1]);
        uint32_t pa2B0 = (uint32_t)__builtin_amdgcn_ds_bpermute(a2, (int)dB[0]);
        uint32_t pa2B1 = (uint32_t)__builtin_amdgcn_ds_bpermute(a2, (int)dB[1]);
        v8h B20 = mkv8h(glo ? pa1A0 : pa1A1,
                        glo ? pa1B0 : pa1B1,
                        glo ? pa2A0 : pa2A1,
                        glo ? pa2B0 : pa2B1);
        uint32_t qa1A2 = (uint32_t)__builtin_amdgcn_ds_bpermute(a1, (int)dA[2]);
        uint32_t qa1A3 = (uint32_t)__builtin_amdgcn_ds_bpermute(a1, (int)dA[3]);
        uint32_t qa1B2 = (uint32_t)__builtin_amdgcn_ds_bpermute(a1, (int)dB[2]);
        uint32_t qa1B3 = (uint32_t)__builtin_amdgcn_ds_bpermute(a1, (int)dB[3]);
        uint32_t qa2A2 = (uint32_t)__builtin_amdgcn_ds_bpermute(a2, (int)dA[2]);
        uint32_t qa2A3 = (uint32_t)__builtin_amdgcn_ds_bpermute(a2, (int)dA[3]);
        uint32_t qa2B2 = (uint32_t)__builtin_amdgcn_ds_bpermute(a2, (int)dB[2]);
        uint32_t qa2B3 = (uint32_t)__builtin_amdgcn_ds_bpermute(a2, (int)dB[3]);
        v8h B21 = mkv8h(glo ? qa1A2 : qa1A3,
                        glo ? qa1B2 : qa1B3,
                        glo ? qa2A2 : qa2A3,
                        glo ? qa2B2 : qa2B3);

        // ---- layer 2: 2 och-tiles, K=64, relu, pack ----
        uint32_t dA2[2], dB2[2];
        #pragma unroll
        for (int mt = 0; mt < 2; mt++) {
            v4f D = {b2v[mt][0], b2v[mt][1], b2v[mt][2], b2v[mt][3]};
            D = __builtin_amdgcn_mfma_f32_16x16x32_f16(A0w2[mt], B20, D, 0, 0, 0);
            D = __builtin_amdgcn_mfma_f32_16x16x32_f16(A1w2[mt], B21, D, 0, 0, 0);
            dA2[mt] = pkh(fmaxf(D[0], 0.f), fmaxf(D[1], 0.f));
            dB2[mt] = pkh(fmaxf(D[2], 0.f), fmaxf(D[3], 0.f));
        }

        // ---- transition 2: h2 -> B3 (same post-select pattern) ----
        uint32_t ra1A0 = (uint32_t)__builtin_amdgcn_ds_bpermute(a1, (int)dA2[0]);
        uint32_t ra1A1 = (uint32_t)__builtin_amdgcn_ds_bpermute(a1, (int)dA2[1]);
        uint32_t ra1B0 = (uint32_t)__builtin_amdgcn_ds_bpermute(a1, (int)dB2[0]);
        uint32_t ra1B1 = (uint32_t)__builtin_amdgcn_ds_bpermute(a1, (int)dB2[1]);
        uint32_t ra2A0 = (uint32_t)__builtin_amdgcn_ds_bpermute(a2, (int)dA2[0]);
        uint32_t ra2A1 = (uint32_t)__builtin_amdgcn_ds_bpermute(a2, (int)dA2[1]);
        uint32_t ra2B0 = (uint32_t)__builtin_amdgcn_ds_bpermute(a2, (int)dB2[0]);
        uint32_t ra2B1 = (uint32_t)__builtin_amdgcn_ds_bpermute(a2, (int)dB2[1]);
        v8h B3 = mkv8h(glo ? ra1A0 : ra1A1,
                       glo ? ra1B0 : ra1B1,
                       glo ? ra2A0 : ra2A1,
                       glo ? ra2B0 : ra2B1);

        // ---- layer 3: 4 och-tiles, K=32, sigmoid, signed LDS scatter ----
        float* sap = &sagg[0][0] + own_c * 68 + 4 * g;
        #pragma unroll
        for (int mt = 0; mt < 4; mt++) {
            v4f D = {b3v[mt][0], b3v[mt][1], b3v[mt][2], b3v[mt][3]};
            D = __builtin_amdgcn_mfma_f32_16x16x32_f16(A0w3[mt], B3, D, 0, 0, 0);
            #pragma unroll
            for (int r = 0; r < 4; r++) {
                float s = sgn_c / (1.0f + __expf(-D[r]));
                atomicAdd(sap + 16 * mt + r, s);          // ds_add_f32
            }
        }

        // ---- rotate pipeline ----
        base = nbase;
        entn_raw = entnn;
        q0c = q0n; q1c = q1n; wc = wn;
        own_c = own_n; sgn_c = sgn_n;
    }

    __syncthreads();

    // ---- fused node MLP: 65 -> 12 -> 1 ----
    if (tid < nvalid) {
        float nh[NHID];
        #pragma unroll
        for (int j = 0; j < NHID; j++) nh[j] = sb4[j];
        const float* ar = &sagg[tid][0];
        #pragma unroll
        for (int k = 0; k < EOUT; k++) {
            float v = ar[k];
            const float* wr = sW4 + k * NHID;
            #pragma unroll
            for (int j = 0; j < NHID; j++) nh[j] = fmaf(v, wr[j], nh[j]);
        }
        {
            float v = lp[(size_t)b * N_ + node0 + tid];
            const float* wr = sW4 + EOUT * NHID;
            #pragma unroll
            for (int j = 0; j < NHID; j++) nh[j] = fmaf(v, wr[j], nh[j]);
        }
        float acc = sb5v;
        #pragma unroll
        for (int j = 0; j < NHID; j++) acc = fmaf(fmaxf(nh[j], 0.f), sW5[j], acc);
        out[(size_t)b * N_ + node0 + tid] = 1.0f / (1.0f + __expf(-acc));
    }
}

// ---------------- launch ----------------

extern "C" void kernel_launch(void* const* d_in, const int* in_sizes, int n_in,
                              void* d_out, int out_size, void* d_ws, size_t ws_size,
                              hipStream_t stream)
{
    const float* nf   = (const float*)d_in[0];
    const float* ew   = (const float*)d_in[1];
    const float* lp   = (const float*)d_in[2];
    const int*   esrc = (const int*)d_in[3];
    const int*   etgt = (const int*)d_in[4];
    const float* W1 = (const float*)d_in[5],  *b1 = (const float*)d_in[6];
    const float* W2 = (const float*)d_in[7],  *b2 = (const float*)d_in[8];
    const float* W3 = (const float*)d_in[9],  *b3 = (const float*)d_in[10];
    const float* W4 = (const float*)d_in[11], *b4 = (const float*)d_in[12];
    const float* W5 = (const float*)d_in[13], *b5 = (const float*)d_in[14];

    float* out = (float*)d_out;
    char*  ws  = (char*)d_ws;

    int*   counts  = (int*)(ws + 0);
    int*   offsets = (int*)(ws + 2048);
    int*   cursors = (int*)(ws + 4096);
    uint2* entries = (uint2*)(ws + 8192);

    (void)hipMemsetAsync(counts, 0, 2048, stream);
    hist_kernel<<<HB, 256, 0, stream>>>(esrc, etgt, counts);
    scan_kernel<<<1, 512, 0, stream>>>(counts, offsets, cursors);
    fill_kernel<<<HB, 256, 0, stream>>>(esrc, etgt, cursors, entries);

    dim3 cg(NCHUNK, B_);
    chunk_kernel<<<cg, 256, 0, stream>>>(nf, ew, lp, entries, offsets,
                                         W1, b1, W2, b2, W3, b3,
                                         W4, b4, W5, b5, out);
}